// Round 7
// baseline (218.329 us; speedup 1.0000x reference)
//
#include <hip/hip_runtime.h>

#define C 256
#define HW 4096
#define CHW (C*HW)            // 1048576 elements per batch per tensor (2^20)
#define CPG 8
#define GELEMS (CPG*HW)

typedef __attribute__((ext_vector_type(8))) short short8;     // 8 bf16 = 4 VGPRs
typedef __attribute__((ext_vector_type(4))) float floatx4;    // 16x16 C/D frag
typedef __attribute__((ext_vector_type(16))) float floatx16;  // 32x32 C/D frag

__device__ __forceinline__ unsigned short f2bf(float x) {
  union { float f; unsigned int u; } v; v.f = x;
  unsigned int r = v.u + 0x7FFF + ((v.u >> 16) & 1);   // RNE
  return (unsigned short)(r >> 16);
}
__device__ __forceinline__ float bf2f(unsigned short u) {
  union { float f; unsigned int v; } x; x.v = ((unsigned int)u) << 16; return x.f;
}

// LDS-only barrier (lgkmcnt drain, NO vmcnt drain). r5 A/B vs __syncthreads
// was null in the 2-barrier loop (waits just moved to consumers), but it is
// REQUIRED here: the single-barrier loop must keep V-tile and K-prefetch
// global loads in flight across the barrier (consumed after it).
__device__ __forceinline__ void lds_barrier() {
  asm volatile("s_waitcnt lgkmcnt(0)" ::: "memory");
  __builtin_amdgcn_s_barrier();
  asm volatile("" ::: "memory");
}

// ---------------- GroupNorm -> hT (b,s,c) bf16  +  weight cast ----------------
__global__ __launch_bounds__(256) void gn_kernel(const float* __restrict__ x,
    const float* __restrict__ gw, const float* __restrict__ gb,
    unsigned short* __restrict__ hT,
    const float* __restrict__ wq, const float* __restrict__ wk,
    const float* __restrict__ wv, const float* __restrict__ wp,
    unsigned short* __restrict__ wbuf) {
  int blk = blockIdx.x;
  int t = threadIdx.x;

  if (blk >= 256) {
    int r = blk - 256;
    int y = r >> 3, sub = r & 7;
    const float* src = (y == 0) ? wq : (y == 1) ? wk : (y == 2) ? wv : wp;
    int i = sub * 8192 + t * 4;
    float4 v = *(const float4*)(src + i);
    ushort4 u;
    u.x = f2bf(v.x); u.y = f2bf(v.y); u.z = f2bf(v.z); u.w = f2bf(v.w);
    *(ushort4*)(wbuf + y * 65536 + i) = u;
    return;
  }

  int gq = blk >> 1, halfg = blk & 1;   // group 0..127 (b*32+g), half 0/1
  int b = gq >> 5, g = gq & 31;
  const float* xg = x + (size_t)gq * GELEMS;
  const float4* x4 = (const float4*)xg;

  float s = 0.f, ss = 0.f;
  for (int i = t; i < GELEMS/4; i += 256) {
    float4 v = x4[i];
    s  += v.x + v.y + v.z + v.w;
    ss += v.x*v.x + v.y*v.y + v.z*v.z + v.w*v.w;
  }
  #pragma unroll
  for (int off = 32; off > 0; off >>= 1) {
    s  += __shfl_down(s,  off, 64);
    ss += __shfl_down(ss, off, 64);
  }
  __shared__ float rs[4], rss[4];
  __shared__ float smean, sinv;
  int wid = t >> 6;
  if ((t & 63) == 0) { rs[wid] = s; rss[wid] = ss; }
  __syncthreads();
  if (t == 0) {
    float S  = rs[0] + rs[1] + rs[2] + rs[3];
    float SS = rss[0] + rss[1] + rss[2] + rss[3];
    float mean = S / (float)GELEMS;
    float var  = SS / (float)GELEMS - mean * mean;
    smean = mean;
    sinv  = rsqrtf(var + 1e-5f);
  }
  __syncthreads();
  float mean = smean, inv = sinv;
  float sa[8], sb[8];
  #pragma unroll
  for (int cc = 0; cc < 8; ++cc) {
    sa[cc] = inv * gw[g*CPG + cc];
    sb[cc] = gb[g*CPG + cc] - mean * sa[cc];
  }
  int sbeg = halfg * 2048;
  #pragma unroll
  for (int p = 0; p < 8; ++p) {
    int sl = sbeg + p*256 + t;
    short8 pk;
    #pragma unroll
    for (int cc = 0; cc < 8; ++cc)
      pk[cc] = (short)f2bf(xg[cc*HW + sl] * sa[cc] + sb[cc]);
    *(short8*)&hT[((size_t)b*HW + sl) * 256 + g*CPG] = pk;
  }
}

// ---------------- fused QKV GEMM ----------
// q,k: fp8 e4m3 (s,c) layout, UNSCALED (C^-0.5 folded into att's exp).
// v: bf16 MFMA-B-fragment packed tiles (16s x 32c, 1 KB each).
__global__ __launch_bounds__(256) void qkv_kernel(const unsigned short* __restrict__ hT,
    const unsigned short* __restrict__ wqb, const float* __restrict__ bq,
    const unsigned short* __restrict__ wkb, const float* __restrict__ bk,
    const unsigned short* __restrict__ wvb, const float* __restrict__ bv,
    unsigned char* __restrict__ qo, unsigned char* __restrict__ ko,
    unsigned short* __restrict__ vo) {
  int stile = blockIdx.x, which = blockIdx.y, b = blockIdx.z;
  int t = threadIdx.x, w = t >> 6, lane = t & 63;
  int n16 = lane & 15, q8 = lane >> 4;
  int s0 = stile * 64;
  const unsigned short* hB = hT + (size_t)b * CHW;
  const unsigned short* W = (which == 0) ? wqb : (which == 1) ? wkb : wvb;
  const float* bias = (which == 0) ? bq : (which == 1) ? bk : bv;

  floatx4 acc[4][4];
  #pragma unroll
  for (int i = 0; i < 4; ++i)
    #pragma unroll
    for (int j = 0; j < 4; ++j) acc[i][j] = (floatx4){0.f,0.f,0.f,0.f};

  for (int kt = 0; kt < 8; ++kt) {
    short8 af[4], bf[4];
    #pragma unroll
    for (int mt = 0; mt < 4; ++mt)
      af[mt] = *(const short8*)&hB[(size_t)(s0 + mt*16 + n16) * 256 + kt*32 + q8*8];
    #pragma unroll
    for (int nt = 0; nt < 4; ++nt)
      bf[nt] = *(const short8*)&W[(size_t)(w*64 + nt*16 + n16) * 256 + kt*32 + q8*8];
    #pragma unroll
    for (int mt = 0; mt < 4; ++mt)
      #pragma unroll
      for (int nt = 0; nt < 4; ++nt)
        acc[mt][nt] = __builtin_amdgcn_mfma_f32_16x16x32_bf16(af[mt], bf[nt], acc[mt][nt], 0, 0, 0);
  }
  float bias_v[4];
  #pragma unroll
  for (int nt = 0; nt < 4; ++nt) bias_v[nt] = bias[w*64 + nt*16 + n16];

  if (which < 2) {
    // fp8 scatter stores (s,c); values unscaled
    unsigned char* oB = (which ? ko : qo) + (size_t)b * CHW;
    #pragma unroll
    for (int mt = 0; mt < 4; ++mt)
      #pragma unroll
      for (int nt = 0; nt < 4; ++nt) {
        float v0 = acc[mt][nt][0] + bias_v[nt];
        float v1 = acc[mt][nt][1] + bias_v[nt];
        float v2 = acc[mt][nt][2] + bias_v[nt];
        float v3 = acc[mt][nt][3] + bias_v[nt];
        unsigned int p01 = __builtin_amdgcn_cvt_pk_fp8_f32(v0, v1, 0, false);
        unsigned int p23 = __builtin_amdgcn_cvt_pk_fp8_f32(v2, v3, 0, false);
        int col = w*64 + nt*16 + n16;
        size_t r0 = (size_t)(s0 + mt*16 + q8*4) * 256 + col;
        oB[r0 +   0] = (unsigned char)(p01 & 0xFF);
        oB[r0 + 256] = (unsigned char)((p01 >> 8) & 0xFF);
        oB[r0 + 512] = (unsigned char)(p23 & 0xFF);
        oB[r0 + 768] = (unsigned char)((p23 >> 8) & 0xFF);
      }
  } else {
    // packed bf16 V store
    unsigned short* vB = vo + (size_t)b * CHW;
    #pragma unroll
    for (int mt = 0; mt < 4; ++mt) {
      int st = stile*4 + mt;
      #pragma unroll
      for (int nt = 0; nt < 4; ++nt) {
        int c = w*64 + nt*16 + n16;
        int ct8 = c >> 5, c5 = c & 31;
        #pragma unroll
        for (int r = 0; r < 4; ++r) {
          int sl = q8*4 + r;
          int hh = sl >> 3, e = sl & 7;
          vB[((size_t)st*8 + ct8)*512 + (hh*32 + c5)*8 + e] =
              f2bf(acc[mt][nt][r] + bias_v[nt]);
        }
      }
    }
  }
}

// ---------------- MFMA flash attention: fp8 QK, bf16 PV, split-K halves ----
// qb,kb (b,s,c) fp8; vb packed bf16 B-frag tiles.
// Grid: flat 512 blocks = 2/CU. XCD-aware decode: combo = bid & 7 selects
// (b, half) -> all 64 q-tiles of one (b,half) land on ONE XCD (1.5 MB K+V
// working set L2-resident).
// r5 restructure: DOUBLE-BUFFERED Ks and Ps -> ONE lds_barrier per mc-iter
// (was 2). Hazard proof (cur = it&1 alternates; stage(it) writes Ks[cur^1]):
//   Ks write(it+1) into Ks[cur] vs QK read(it) of Ks[cur]: read precedes
//     barrier(it), write follows it.
//   Ps write(it)/PV read(it): separated by barrier(it).
//   Ps[cur] rewrite(it+2) follows barrier(it+1); PV read(it) precedes every
//     wave's arrival at barrier(it+1).  All cross-wave orders barrier-enforced.
// T5: s_setprio(1) around QK and PV MFMA clusters (wave role-diversity now
// exists per phase; m191 measured +4-7% on attn).
#define KS8_PAD 264  // BYTES per Ks row (256 + 8); b64 reads 4 dwords/bank (min)
#define PS_PAD 72    // shorts per Ps row (64 + 8); b128 reads 8 dwords/bank (min)

__global__ __launch_bounds__(256, 2) void att_kernel(
    const unsigned char* __restrict__ qb,
    const unsigned char* __restrict__ kb,
    const unsigned short* __restrict__ vb,
    unsigned short* __restrict__ P1, unsigned short* __restrict__ P2,
    float* __restrict__ l_arr) {
  __shared__ __align__(16) unsigned char Ks8[2][64 * KS8_PAD];   // 33.8 KB
  __shared__ __align__(16) unsigned short Ps[2][64 * PS_PAD];    // 18.4 KB
  __shared__ float Ls[2][64];
  __shared__ float Lc[64];

  int t = threadIdx.x, w = t >> 6, lane = t & 63;
  int m32 = lane & 31;
  int h   = lane >> 5;
  int qblk = w & 1;
  int mblk = w >> 1;
  int bid = blockIdx.x;
  int combo = bid & 7;              // fixed XCD (round-robin dispatch)
  int half = combo & 1, b = combo >> 1;
  int n0 = (bid >> 3) * 64;

  const unsigned char* qB = qb + (size_t)b * CHW;
  const unsigned char* kB = kb + (size_t)b * CHW;
  const unsigned short* vB = vb + (size_t)b * CHW;

  // Q fragments (fp8 A operand, 32x32x16): lane row n0+qblk*32+m32, k bytes h*8+e
  long qf8[16];
  {
    const unsigned char* qp = qB + (size_t)(n0 + qblk*32 + m32) * 256 + h*8;
    #pragma unroll
    for (int ks = 0; ks < 16; ++ks) qf8[ks] = *(const long*)(qp + ks*16);
  }

  float lsum[16];
  #pragma unroll
  for (int r = 0; r < 16; ++r) lsum[r] = 0.f;
  floatx16 oacc[2][2];   // [qt][ct]
  #pragma unroll
  for (int i = 0; i < 2; ++i)
    #pragma unroll
    for (int j = 0; j < 2; ++j)
      #pragma unroll
      for (int r = 0; r < 16; ++r) oacc[i][j][r] = 0.f;

  // staging: K chunk = 64 rows x 256 B; thread t covers row t>>2, 64 B at (t&3)*64
  int krow = t >> 2, kcb = (t & 3) * 64;
  int mc_beg = half * 32, mc_end = mc_beg + 32;
  uint4 kreg[4];

  // prologue: stage chunk mc_beg into Ks[0]; issue kreg for chunk mc_beg+1
  #pragma unroll
  for (int i = 0; i < 4; ++i)
    kreg[i] = *(const uint4*)(kB + (size_t)(mc_beg*64 + krow) * 256 + kcb + i*16);
  #pragma unroll
  for (int i = 0; i < 4; ++i) {
    *(uint2*)&Ks8[0][krow * KS8_PAD + kcb + i*16]     = make_uint2(kreg[i].x, kreg[i].y);
    *(uint2*)&Ks8[0][krow * KS8_PAD + kcb + i*16 + 8] = make_uint2(kreg[i].z, kreg[i].w);
  }
  #pragma unroll
  for (int i = 0; i < 4; ++i)
    kreg[i] = *(const uint4*)(kB + (size_t)((mc_beg+1)*64 + krow) * 256 + kcb + i*16);
  lds_barrier();

  for (int it = 0; it < 32; ++it) {
    int mc = mc_beg + it;
    int cur = it & 1;
    // stage NEXT chunk into Ks[cur^1] (kreg holds chunk mc+1)
    if (mc + 1 < mc_end) {
      #pragma unroll
      for (int i = 0; i < 4; ++i) {
        *(uint2*)&Ks8[cur^1][krow * KS8_PAD + kcb + i*16]     = make_uint2(kreg[i].x, kreg[i].y);
        *(uint2*)&Ks8[cur^1][krow * KS8_PAD + kcb + i*16 + 8] = make_uint2(kreg[i].z, kreg[i].w);
      }
      if (mc + 2 < mc_end) {
        #pragma unroll
        for (int i = 0; i < 4; ++i)
          kreg[i] = *(const uint4*)(kB + (size_t)((mc+2)*64 + krow) * 256 + kcb + i*16);
      }
    }
    // V B-fragments: packed bf16 tiles, 1 coalesced b128 each (consumed at PV)
    short8 vreg[4][2];
    #pragma unroll
    for (int ks2 = 0; ks2 < 4; ++ks2)
      #pragma unroll
      for (int ct = 0; ct < 2; ++ct)
        vreg[ks2][ct] = *(const short8*)(vB +
            ((size_t)(mc*4 + ks2)*8 + (w*2 + ct))*512 + lane*8);

    // ---- S = Q·K^T (fp8) from Ks[cur]: 2 independent 8-step chains ----
    floatx16 sa_, sb_;
    #pragma unroll
    for (int r = 0; r < 16; ++r) { sa_[r] = 0.f; sb_[r] = 0.f; }
    __builtin_amdgcn_s_setprio(1);
    #pragma unroll
    for (int ks = 0; ks < 8; ++ks) {
      long bk0 = *(const long*)&Ks8[cur][(mblk*32 + m32) * KS8_PAD + ks*16 + h*8];
      long bk1 = *(const long*)&Ks8[cur][(mblk*32 + m32) * KS8_PAD + (ks+8)*16 + h*8];
      sa_ = __builtin_amdgcn_mfma_f32_32x32x16_fp8_fp8(qf8[ks],   bk0, sa_, 0, 0, 0);
      sb_ = __builtin_amdgcn_mfma_f32_32x32x16_fp8_fp8(qf8[ks+8], bk1, sb_, 0, 0, 0);
    }
    __builtin_amdgcn_s_setprio(0);
    // ---- no-max softmax (C^-0.5 folded into exp); row reduction deferred ----
    #pragma unroll
    for (int reg = 0; reg < 16; ++reg) {
      float e = __expf((sa_[reg] + sb_[reg]) * 0.0625f);
      lsum[reg] += e;
      int qr = qblk*32 + (reg & 3) + 8*(reg >> 2) + 4*h;
      Ps[cur][qr * PS_PAD + mblk*32 + m32] = f2bf(e);
    }
    lds_barrier();   // the ONLY barrier: Ks[cur^1]+Ps[cur] published together
    // ---- O += P·V (bf16) from Ps[cur] ----
    __builtin_amdgcn_s_setprio(1);
    #pragma unroll
    for (int ks2 = 0; ks2 < 4; ++ks2) {
      short8 pf[2];
      #pragma unroll
      for (int qt = 0; qt < 2; ++qt)
        pf[qt] = *(const short8*)&Ps[cur][(qt*32 + m32) * PS_PAD + ks2*16 + h*8];
      #pragma unroll
      for (int qt = 0; qt < 2; ++qt)
        #pragma unroll
        for (int ct = 0; ct < 2; ++ct)
          oacc[qt][ct] = __builtin_amdgcn_mfma_f32_32x32x16_bf16(pf[qt], vreg[ks2][ct], oacc[qt][ct], 0, 0, 0);
    }
    __builtin_amdgcn_s_setprio(0);
  }

  // ---- epilogue: reduce l, normalize, write partial (n,c) + l ----
  #pragma unroll
  for (int reg = 0; reg < 16; ++reg) {
    float v = lsum[reg];
    v += __shfl_xor(v, 1);  v += __shfl_xor(v, 2);
    v += __shfl_xor(v, 4);  v += __shfl_xor(v, 8);
    v += __shfl_xor(v, 16);
    lsum[reg] = v;
  }
  if (m32 == 0) {
    #pragma unroll
    for (int reg = 0; reg < 16; ++reg) {
      int qr = qblk*32 + (reg & 3) + 8*(reg >> 2) + 4*h;
      Ls[mblk][qr] = lsum[reg];
    }
  }
  __syncthreads();
  if (t < 64) {
    float l = Ls[0][t] + Ls[1][t];
    l_arr[half * 16384 + b * 4096 + n0 + t] = l;
    Lc[t] = 1.f / l;
  }
  __syncthreads();
  unsigned short* pB = (half ? P2 : P1) + (size_t)b * CHW;
  #pragma unroll
  for (int qt = 0; qt < 2; ++qt)
    #pragma unroll
    for (int reg = 0; reg < 16; ++reg) {
      int q = qt*32 + (reg & 3) + 8*(reg >> 2) + 4*h;
      float linv = Lc[q];
      #pragma unroll
      for (int ct = 0; ct < 2; ++ct)
        pB[(size_t)(n0 + q) * 256 + w*64 + ct*32 + m32] =
            f2bf(oacc[qt][ct][reg] * linv);
    }
}

// ---------------- proj GEMM + inline merge + bias + residual, 512 blocks ----
// XCD-aware decode: combo = bid & 7 -> (b, stile-half); the 4 ox blocks that
// read the SAME 128 KB P1/P2 s-tile are 8 apart in bid -> same XCD -> L2 reuse.
__global__ __launch_bounds__(256) void proj_kernel(const unsigned short* __restrict__ P1,
    const unsigned short* __restrict__ P2, const float* __restrict__ l_arr,
    const unsigned short* __restrict__ wpb, const float* __restrict__ bp,
    const float* __restrict__ x, float* __restrict__ out) {
  int bid = blockIdx.x;
  int combo = bid & 7, id = bid >> 3;
  int b = combo >> 1;
  int stile = (combo & 1) * 16 + (id & 15);
  int ox = id >> 4;
  int t = threadIdx.x, w = t >> 6, lane = t & 63;
  int n16 = lane & 15, q8 = lane >> 4;
  int o0 = ox * 64;
  int sBase = stile * 128 + w * 32;
  const unsigned short* p1B = P1 + (size_t)b * CHW;
  const unsigned short* p2B = P2 + (size_t)b * CHW;

  float w1v[2], w2v[2];
  #pragma unroll
  for (int nt = 0; nt < 2; ++nt) {
    int s = sBase + nt*16 + n16;
    float l1 = l_arr[b*4096 + s], l2 = l_arr[16384 + b*4096 + s];
    float inv = 1.f / (l1 + l2);
    w1v[nt] = l1 * inv; w2v[nt] = l2 * inv;
  }
  float4 bias4[4];
  #pragma unroll
  for (int mt = 0; mt < 4; ++mt)
    bias4[mt] = *(const float4*)&bp[o0 + mt*16 + q8*4];

  floatx4 acc[4][2];
  #pragma unroll
  for (int i = 0; i < 4; ++i)
    #pragma unroll
    for (int j = 0; j < 2; ++j) acc[i][j] = (floatx4){0.f,0.f,0.f,0.f};

  for (int kt = 0; kt < 8; ++kt) {
    short8 af[4], bf[2];
    #pragma unroll
    for (int mt = 0; mt < 4; ++mt)
      af[mt] = *(const short8*)&wpb[(size_t)(o0 + mt*16 + n16) * 256 + kt*32 + q8*8];
    #pragma unroll
    for (int nt = 0; nt < 2; ++nt) {
      size_t off = (size_t)(sBase + nt*16 + n16) * 256 + kt*32 + q8*8;
      short8 a = *(const short8*)&p1B[off];
      short8 c = *(const short8*)&p2B[off];
      #pragma unroll
      for (int j = 0; j < 8; ++j)
        bf[nt][j] = (short)f2bf(w1v[nt] * bf2f((unsigned short)a[j]) +
                                w2v[nt] * bf2f((unsigned short)c[j]));
    }
    #pragma unroll
    for (int mt = 0; mt < 4; ++mt)
      #pragma unroll
      for (int nt = 0; nt < 2; ++nt)
        acc[mt][nt] = __builtin_amdgcn_mfma_f32_16x16x32_bf16(af[mt], bf[nt], acc[mt][nt], 0, 0, 0);
  }
  const float* xB = x + (size_t)b * CHW;
  float* oB = out + (size_t)b * CHW;
  #pragma unroll
  for (int mt = 0; mt < 4; ++mt)
    #pragma unroll
    for (int nt = 0; nt < 2; ++nt) {
      float bb[4] = {bias4[mt].x, bias4[mt].y, bias4[mt].z, bias4[mt].w};
      #pragma unroll
      for (int r = 0; r < 4; ++r) {
        size_t idx = (size_t)(o0 + mt*16 + q8*4 + r) * HW + sBase + nt*16 + n16;
        oB[idx] = xB[idx] + bb[r] + acc[mt][nt][r];
      }
    }
}

extern "C" void kernel_launch(void* const* d_in, const int* in_sizes, int n_in,
                              void* d_out, int out_size, void* d_ws, size_t ws_size,
                              hipStream_t stream) {
  const float* x  = (const float*)d_in[0];
  const float* gw = (const float*)d_in[1];
  const float* gb = (const float*)d_in[2];
  const float* wq = (const float*)d_in[3];
  const float* bq = (const float*)d_in[4];
  const float* wk = (const float*)d_in[5];
  const float* bk = (const float*)d_in[6];
  const float* wv = (const float*)d_in[7];
  const float* bv = (const float*)d_in[8];
  const float* wp = (const float*)d_in[9];
  const float* bp = (const float*)d_in[10];
  float* out = (float*)d_out;
  float* ws  = (float*)d_ws;

  // units of CHW floats (4 MiB each):
  unsigned short* hT    = (unsigned short*)ws;                      // 0-1
  unsigned char*  qbp   = (unsigned char*)(ws + (size_t)2*CHW);     // 2 (fp8, 4 MB)
  unsigned char*  kbp   = (unsigned char*)(ws + (size_t)4*CHW);     // 4 (fp8, 4 MB)
  unsigned short* vbp   = (unsigned short*)(ws + (size_t)6*CHW);    // 6-7 (packed bf16)
  unsigned short* P1    = (unsigned short*)(ws + (size_t)8*CHW);    // 8-9
  unsigned short* P2    = (unsigned short*)(ws + (size_t)10*CHW);   // 10-11
  float*          l_arr = ws + (size_t)12*CHW;                      // 32768 floats
  unsigned short* wbuf  = (unsigned short*)(ws + (size_t)12*CHW + 65536); // 512 KB

  unsigned short* wqb = wbuf;
  unsigned short* wkb = wbuf + 65536;
  unsigned short* wvb = wbuf + 2*65536;
  unsigned short* wpb = wbuf + 3*65536;

  gn_kernel<<<dim3(288), dim3(256), 0, stream>>>(x, gw, gb, hT, wq, wk, wv, wp, wbuf);
  qkv_kernel<<<dim3(64, 3, 4), dim3(256), 0, stream>>>(hT, wqb, bq, wkb, bk, wvb, bv, qbp, kbp, vbp);
  att_kernel<<<dim3(512), dim3(256), 0, stream>>>(qbp, kbp, vbp, P1, P2, l_arr);
  proj_kernel<<<dim3(512), dim3(256), 0, stream>>>(P1, P2, l_arr, wpb, bp, x, out);
}

// Round 8
// 214.036 us; speedup vs baseline: 1.0201x; 1.0201x over previous
//
#include <hip/hip_runtime.h>

#define C 256
#define HW 4096
#define CHW (C*HW)            // 1048576 elements per batch per tensor (2^20)
#define CPG 8
#define GELEMS (CPG*HW)

typedef __attribute__((ext_vector_type(8))) short short8;     // 8 bf16 = 4 VGPRs
typedef __attribute__((ext_vector_type(4))) float floatx4;    // 16x16 C/D frag
typedef __attribute__((ext_vector_type(16))) float floatx16;  // 32x32 C/D frag

__device__ __forceinline__ unsigned short f2bf(float x) {
  union { float f; unsigned int u; } v; v.f = x;
  unsigned int r = v.u + 0x7FFF + ((v.u >> 16) & 1);   // RNE
  return (unsigned short)(r >> 16);
}
__device__ __forceinline__ float bf2f(unsigned short u) {
  union { float f; unsigned int v; } x; x.v = ((unsigned int)u) << 16; return x.f;
}

// ---------------- GroupNorm -> hT (b,s,c) bf16  +  weight cast ----------------
__global__ __launch_bounds__(256) void gn_kernel(const float* __restrict__ x,
    const float* __restrict__ gw, const float* __restrict__ gb,
    unsigned short* __restrict__ hT,
    const float* __restrict__ wq, const float* __restrict__ wk,
    const float* __restrict__ wv, const float* __restrict__ wp,
    unsigned short* __restrict__ wbuf) {
  int blk = blockIdx.x;
  int t = threadIdx.x;

  if (blk >= 256) {
    int r = blk - 256;
    int y = r >> 3, sub = r & 7;
    const float* src = (y == 0) ? wq : (y == 1) ? wk : (y == 2) ? wv : wp;
    int i = sub * 8192 + t * 4;
    float4 v = *(const float4*)(src + i);
    ushort4 u;
    u.x = f2bf(v.x); u.y = f2bf(v.y); u.z = f2bf(v.z); u.w = f2bf(v.w);
    *(ushort4*)(wbuf + y * 65536 + i) = u;
    return;
  }

  int gq = blk >> 1, halfg = blk & 1;   // group 0..127 (b*32+g), half 0/1
  int b = gq >> 5, g = gq & 31;
  const float* xg = x + (size_t)gq * GELEMS;
  const float4* x4 = (const float4*)xg;

  float s = 0.f, ss = 0.f;
  for (int i = t; i < GELEMS/4; i += 256) {
    float4 v = x4[i];
    s  += v.x + v.y + v.z + v.w;
    ss += v.x*v.x + v.y*v.y + v.z*v.z + v.w*v.w;
  }
  #pragma unroll
  for (int off = 32; off > 0; off >>= 1) {
    s  += __shfl_down(s,  off, 64);
    ss += __shfl_down(ss, off, 64);
  }
  __shared__ float rs[4], rss[4];
  __shared__ float smean, sinv;
  int wid = t >> 6;
  if ((t & 63) == 0) { rs[wid] = s; rss[wid] = ss; }
  __syncthreads();
  if (t == 0) {
    float S  = rs[0] + rs[1] + rs[2] + rs[3];
    float SS = rss[0] + rss[1] + rss[2] + rss[3];
    float mean = S / (float)GELEMS;
    float var  = SS / (float)GELEMS - mean * mean;
    smean = mean;
    sinv  = rsqrtf(var + 1e-5f);
  }
  __syncthreads();
  float mean = smean, inv = sinv;
  float sa[8], sb[8];
  #pragma unroll
  for (int cc = 0; cc < 8; ++cc) {
    sa[cc] = inv * gw[g*CPG + cc];
    sb[cc] = gb[g*CPG + cc] - mean * sa[cc];
  }
  int sbeg = halfg * 2048;
  #pragma unroll
  for (int p = 0; p < 8; ++p) {
    int sl = sbeg + p*256 + t;
    short8 pk;
    #pragma unroll
    for (int cc = 0; cc < 8; ++cc)
      pk[cc] = (short)f2bf(xg[cc*HW + sl] * sa[cc] + sb[cc]);
    *(short8*)&hT[((size_t)b*HW + sl) * 256 + g*CPG] = pk;
  }
}

// ---------------- fused QKV GEMM ----------
// q,k: fp8 e4m3 (s,c) layout, UNSCALED (C^-0.5 folded into att's exp).
// v: bf16 MFMA-B-fragment packed tiles (16s x 32c, 1 KB each).
__global__ __launch_bounds__(256) void qkv_kernel(const unsigned short* __restrict__ hT,
    const unsigned short* __restrict__ wqb, const float* __restrict__ bq,
    const unsigned short* __restrict__ wkb, const float* __restrict__ bk,
    const unsigned short* __restrict__ wvb, const float* __restrict__ bv,
    unsigned char* __restrict__ qo, unsigned char* __restrict__ ko,
    unsigned short* __restrict__ vo) {
  int stile = blockIdx.x, which = blockIdx.y, b = blockIdx.z;
  int t = threadIdx.x, w = t >> 6, lane = t & 63;
  int n16 = lane & 15, q8 = lane >> 4;
  int s0 = stile * 64;
  const unsigned short* hB = hT + (size_t)b * CHW;
  const unsigned short* W = (which == 0) ? wqb : (which == 1) ? wkb : wvb;
  const float* bias = (which == 0) ? bq : (which == 1) ? bk : bv;

  floatx4 acc[4][4];
  #pragma unroll
  for (int i = 0; i < 4; ++i)
    #pragma unroll
    for (int j = 0; j < 4; ++j) acc[i][j] = (floatx4){0.f,0.f,0.f,0.f};

  for (int kt = 0; kt < 8; ++kt) {
    short8 af[4], bf[4];
    #pragma unroll
    for (int mt = 0; mt < 4; ++mt)
      af[mt] = *(const short8*)&hB[(size_t)(s0 + mt*16 + n16) * 256 + kt*32 + q8*8];
    #pragma unroll
    for (int nt = 0; nt < 4; ++nt)
      bf[nt] = *(const short8*)&W[(size_t)(w*64 + nt*16 + n16) * 256 + kt*32 + q8*8];
    #pragma unroll
    for (int mt = 0; mt < 4; ++mt)
      #pragma unroll
      for (int nt = 0; nt < 4; ++nt)
        acc[mt][nt] = __builtin_amdgcn_mfma_f32_16x16x32_bf16(af[mt], bf[nt], acc[mt][nt], 0, 0, 0);
  }
  float bias_v[4];
  #pragma unroll
  for (int nt = 0; nt < 4; ++nt) bias_v[nt] = bias[w*64 + nt*16 + n16];

  if (which < 2) {
    // fp8 scatter stores (s,c); values unscaled
    unsigned char* oB = (which ? ko : qo) + (size_t)b * CHW;
    #pragma unroll
    for (int mt = 0; mt < 4; ++mt)
      #pragma unroll
      for (int nt = 0; nt < 4; ++nt) {
        float v0 = acc[mt][nt][0] + bias_v[nt];
        float v1 = acc[mt][nt][1] + bias_v[nt];
        float v2 = acc[mt][nt][2] + bias_v[nt];
        float v3 = acc[mt][nt][3] + bias_v[nt];
        unsigned int p01 = __builtin_amdgcn_cvt_pk_fp8_f32(v0, v1, 0, false);
        unsigned int p23 = __builtin_amdgcn_cvt_pk_fp8_f32(v2, v3, 0, false);
        int col = w*64 + nt*16 + n16;
        size_t r0 = (size_t)(s0 + mt*16 + q8*4) * 256 + col;
        oB[r0 +   0] = (unsigned char)(p01 & 0xFF);
        oB[r0 + 256] = (unsigned char)((p01 >> 8) & 0xFF);
        oB[r0 + 512] = (unsigned char)(p23 & 0xFF);
        oB[r0 + 768] = (unsigned char)((p23 >> 8) & 0xFF);
      }
  } else {
    // packed bf16 V store
    unsigned short* vB = vo + (size_t)b * CHW;
    #pragma unroll
    for (int mt = 0; mt < 4; ++mt) {
      int st = stile*4 + mt;
      #pragma unroll
      for (int nt = 0; nt < 4; ++nt) {
        int c = w*64 + nt*16 + n16;
        int ct8 = c >> 5, c5 = c & 31;
        #pragma unroll
        for (int r = 0; r < 4; ++r) {
          int sl = q8*4 + r;
          int hh = sl >> 3, e = sl & 7;
          vB[((size_t)st*8 + ct8)*512 + (hh*32 + c5)*8 + e] =
              f2bf(acc[mt][nt][r] + bias_v[nt]);
        }
      }
    }
  }
}

// ---------------- MFMA flash attention: fp8 QK, bf16 PV, split-K halves ----
// REVERTED to the r3-measured-fastest form (76.6 us): single-buffer Ks/Ps,
// plain __syncthreads. Barrier-arc experiments (lds_barrier 78.3, dbuf+setprio
// 80.2) were negative -- att is intra-wave-chain latency-bound (MfmaUtil ~36%
// invariant), not barrier-bound.
// Grid: flat 512 blocks = 2/CU. XCD-aware decode: combo = bid & 7 selects
// (b, half) -> all 64 q-tiles of one (b,half) land on ONE XCD (1.5 MB K+V
// working set L2-resident).
#define KS8_PAD 264  // BYTES per Ks row (256 + 8); b64 reads 4 dwords/bank (min)
#define PS_PAD 72    // shorts per Ps row (64 + 8); b128 reads 8 dwords/bank (min)

__global__ __launch_bounds__(256, 2) void att_kernel(
    const unsigned char* __restrict__ qb,
    const unsigned char* __restrict__ kb,
    const unsigned short* __restrict__ vb,
    unsigned short* __restrict__ P1, unsigned short* __restrict__ P2,
    float* __restrict__ l_arr) {
  __shared__ __align__(16) unsigned char Ks8[64 * KS8_PAD];   // 16.9 KB
  __shared__ __align__(16) unsigned short Ps[64 * PS_PAD];
  __shared__ float Ls[2][64];
  __shared__ float Lc[64];

  int t = threadIdx.x, w = t >> 6, lane = t & 63;
  int m32 = lane & 31;
  int h   = lane >> 5;
  int qblk = w & 1;
  int mblk = w >> 1;
  int bid = blockIdx.x;
  int combo = bid & 7;              // fixed XCD (round-robin dispatch)
  int half = combo & 1, b = combo >> 1;
  int n0 = (bid >> 3) * 64;

  const unsigned char* qB = qb + (size_t)b * CHW;
  const unsigned char* kB = kb + (size_t)b * CHW;
  const unsigned short* vB = vb + (size_t)b * CHW;

  // Q fragments (fp8 A operand, 32x32x16): lane row n0+qblk*32+m32, k bytes h*8+e
  long qf8[16];
  {
    const unsigned char* qp = qB + (size_t)(n0 + qblk*32 + m32) * 256 + h*8;
    #pragma unroll
    for (int ks = 0; ks < 16; ++ks) qf8[ks] = *(const long*)(qp + ks*16);
  }

  float lsum[16];
  #pragma unroll
  for (int r = 0; r < 16; ++r) lsum[r] = 0.f;
  floatx16 oacc[2][2];   // [qt][ct]
  #pragma unroll
  for (int i = 0; i < 2; ++i)
    #pragma unroll
    for (int j = 0; j < 2; ++j)
      #pragma unroll
      for (int r = 0; r < 16; ++r) oacc[i][j][r] = 0.f;

  // staging: K chunk = 64 rows x 256 B; thread t covers row t>>2, 64 B at (t&3)*64
  int krow = t >> 2, kcb = (t & 3) * 64;
  int mc_beg = half * 32, mc_end = mc_beg + 32;
  uint4 kreg[4];
  #pragma unroll
  for (int i = 0; i < 4; ++i)
    kreg[i] = *(const uint4*)(kB + (size_t)(mc_beg*64 + krow) * 256 + kcb + i*16);

  for (int mc = mc_beg; mc < mc_end; ++mc) {
    int m0 = mc * 64;
    // stage current K chunk (b64 writes, pitch 264 B)
    #pragma unroll
    for (int i = 0; i < 4; ++i) {
      *(uint2*)&Ks8[krow * KS8_PAD + kcb + i*16]     = make_uint2(kreg[i].x, kreg[i].y);
      *(uint2*)&Ks8[krow * KS8_PAD + kcb + i*16 + 8] = make_uint2(kreg[i].z, kreg[i].w);
    }
    __syncthreads();
    // prefetch next K chunk
    if (mc + 1 < mc_end) {
      #pragma unroll
      for (int i = 0; i < 4; ++i)
        kreg[i] = *(const uint4*)(kB + (size_t)(m0 + 64 + krow) * 256 + kcb + i*16);
    }
    // V B-fragments: packed bf16 tiles, 1 coalesced b128 each
    short8 vreg[4][2];
    #pragma unroll
    for (int ks2 = 0; ks2 < 4; ++ks2)
      #pragma unroll
      for (int ct = 0; ct < 2; ++ct)
        vreg[ks2][ct] = *(const short8*)(vB +
            ((size_t)(mc*4 + ks2)*8 + (w*2 + ct))*512 + lane*8);

    // ---- S = Q·K^T (fp8): 2 independent 8-step chains ----
    floatx16 sa_, sb_;
    #pragma unroll
    for (int r = 0; r < 16; ++r) { sa_[r] = 0.f; sb_[r] = 0.f; }
    #pragma unroll
    for (int ks = 0; ks < 8; ++ks) {
      long bk0 = *(const long*)&Ks8[(mblk*32 + m32) * KS8_PAD + ks*16 + h*8];
      long bk1 = *(const long*)&Ks8[(mblk*32 + m32) * KS8_PAD + (ks+8)*16 + h*8];
      sa_ = __builtin_amdgcn_mfma_f32_32x32x16_fp8_fp8(qf8[ks],   bk0, sa_, 0, 0, 0);
      sb_ = __builtin_amdgcn_mfma_f32_32x32x16_fp8_fp8(qf8[ks+8], bk1, sb_, 0, 0, 0);
    }
    // ---- no-max softmax with C^-0.5 folded into exp; row reduction deferred ----
    #pragma unroll
    for (int reg = 0; reg < 16; ++reg) {
      float e = __expf((sa_[reg] + sb_[reg]) * 0.0625f);
      lsum[reg] += e;
      int qr = qblk*32 + (reg & 3) + 8*(reg >> 2) + 4*h;
      Ps[qr * PS_PAD + mblk*32 + m32] = f2bf(e);
    }
    __syncthreads();
    // ---- O += P·V (bf16) ----
    #pragma unroll
    for (int ks2 = 0; ks2 < 4; ++ks2) {
      short8 pf[2];
      #pragma unroll
      for (int qt = 0; qt < 2; ++qt)
        pf[qt] = *(const short8*)&Ps[(qt*32 + m32) * PS_PAD + ks2*16 + h*8];
      #pragma unroll
      for (int qt = 0; qt < 2; ++qt)
        #pragma unroll
        for (int ct = 0; ct < 2; ++ct)
          oacc[qt][ct] = __builtin_amdgcn_mfma_f32_32x32x16_bf16(pf[qt], vreg[ks2][ct], oacc[qt][ct], 0, 0, 0);
    }
  }

  // ---- epilogue: reduce l, normalize, write partial (n,c) + l ----
  #pragma unroll
  for (int reg = 0; reg < 16; ++reg) {
    float v = lsum[reg];
    v += __shfl_xor(v, 1);  v += __shfl_xor(v, 2);
    v += __shfl_xor(v, 4);  v += __shfl_xor(v, 8);
    v += __shfl_xor(v, 16);
    lsum[reg] = v;
  }
  if (m32 == 0) {
    #pragma unroll
    for (int reg = 0; reg < 16; ++reg) {
      int qr = qblk*32 + (reg & 3) + 8*(reg >> 2) + 4*h;
      Ls[mblk][qr] = lsum[reg];
    }
  }
  __syncthreads();
  if (t < 64) {
    float l = Ls[0][t] + Ls[1][t];
    l_arr[half * 16384 + b * 4096 + n0 + t] = l;
    Lc[t] = 1.f / l;
  }
  __syncthreads();
  unsigned short* pB = (half ? P2 : P1) + (size_t)b * CHW;
  #pragma unroll
  for (int qt = 0; qt < 2; ++qt)
    #pragma unroll
    for (int reg = 0; reg < 16; ++reg) {
      int q = qt*32 + (reg & 3) + 8*(reg >> 2) + 4*h;
      float linv = Lc[q];
      #pragma unroll
      for (int ct = 0; ct < 2; ++ct)
        pB[(size_t)(n0 + q) * 256 + w*64 + ct*32 + m32] =
            f2bf(oacc[qt][ct][reg] * linv);
    }
}

// ---------------- merge kernel: Pm = w1*P1 + w2*P2 (bf16) ----------------
// Hoists the per-element half-merge OUT of proj, where it was (a) VALU-heavy
// inside the GEMM K-loop and (b) recomputed 4x (once per ox tile) with a
// double P read. Memory-bound: 24 MB traffic ~ 5 us. Numerically identical
// op order to the old in-proj merge.
__global__ __launch_bounds__(256) void merge_kernel(
    const unsigned short* __restrict__ P1, const unsigned short* __restrict__ P2,
    const float* __restrict__ l_arr, unsigned short* __restrict__ Pm) {
  int row = blockIdx.x * 8 + (threadIdx.x >> 5);   // global row in [0,16384)
  int c0 = (threadIdx.x & 31) * 8;
  int b = row >> 12, s = row & 4095;
  float l1 = l_arr[b * 4096 + s], l2 = l_arr[16384 + b * 4096 + s];
  float inv = 1.f / (l1 + l2);
  float w1 = l1 * inv, w2 = l2 * inv;
  size_t off = (size_t)row * 256 + c0;
  short8 a = *(const short8*)&P1[off];
  short8 c = *(const short8*)&P2[off];
  short8 o;
  #pragma unroll
  for (int j = 0; j < 8; ++j)
    o[j] = (short)f2bf(w1 * bf2f((unsigned short)a[j]) +
                       w2 * bf2f((unsigned short)c[j]));
  *(short8*)&Pm[off] = o;
}

// ---------------- proj GEMM + bias + residual, 512 blocks ----------------
// Now a clean GEMM on pre-merged Pm (b,s,c) bf16: K-loop is 6 b128 loads +
// 8 MFMA, no VALU merge. XCD-aware decode: combo = bid & 7 -> (b, stile-half);
// the 4 ox blocks reading the SAME 64 KB Pm s-tile are 8 apart -> same XCD.
__global__ __launch_bounds__(256) void proj_kernel(const unsigned short* __restrict__ Pm,
    const unsigned short* __restrict__ wpb, const float* __restrict__ bp,
    const float* __restrict__ x, float* __restrict__ out) {
  int bid = blockIdx.x;
  int combo = bid & 7, id = bid >> 3;
  int b = combo >> 1;
  int stile = (combo & 1) * 16 + (id & 15);
  int ox = id >> 4;
  int t = threadIdx.x, w = t >> 6, lane = t & 63;
  int n16 = lane & 15, q8 = lane >> 4;
  int o0 = ox * 64;
  int sBase = stile * 128 + w * 32;
  const unsigned short* pmB = Pm + (size_t)b * CHW;

  float4 bias4[4];
  #pragma unroll
  for (int mt = 0; mt < 4; ++mt)
    bias4[mt] = *(const float4*)&bp[o0 + mt*16 + q8*4];

  floatx4 acc[4][2];
  #pragma unroll
  for (int i = 0; i < 4; ++i)
    #pragma unroll
    for (int j = 0; j < 2; ++j) acc[i][j] = (floatx4){0.f,0.f,0.f,0.f};

  for (int kt = 0; kt < 8; ++kt) {
    short8 af[4], bf[2];
    #pragma unroll
    for (int mt = 0; mt < 4; ++mt)
      af[mt] = *(const short8*)&wpb[(size_t)(o0 + mt*16 + n16) * 256 + kt*32 + q8*8];
    #pragma unroll
    for (int nt = 0; nt < 2; ++nt)
      bf[nt] = *(const short8*)&pmB[(size_t)(sBase + nt*16 + n16) * 256 + kt*32 + q8*8];
    #pragma unroll
    for (int mt = 0; mt < 4; ++mt)
      #pragma unroll
      for (int nt = 0; nt < 2; ++nt)
        acc[mt][nt] = __builtin_amdgcn_mfma_f32_16x16x32_bf16(af[mt], bf[nt], acc[mt][nt], 0, 0, 0);
  }
  const float* xB = x + (size_t)b * CHW;
  float* oB = out + (size_t)b * CHW;
  #pragma unroll
  for (int mt = 0; mt < 4; ++mt)
    #pragma unroll
    for (int nt = 0; nt < 2; ++nt) {
      float bb[4] = {bias4[mt].x, bias4[mt].y, bias4[mt].z, bias4[mt].w};
      #pragma unroll
      for (int r = 0; r < 4; ++r) {
        size_t idx = (size_t)(o0 + mt*16 + q8*4 + r) * HW + sBase + nt*16 + n16;
        oB[idx] = xB[idx] + bb[r] + acc[mt][nt][r];
      }
    }
}

extern "C" void kernel_launch(void* const* d_in, const int* in_sizes, int n_in,
                              void* d_out, int out_size, void* d_ws, size_t ws_size,
                              hipStream_t stream) {
  const float* x  = (const float*)d_in[0];
  const float* gw = (const float*)d_in[1];
  const float* gb = (const float*)d_in[2];
  const float* wq = (const float*)d_in[3];
  const float* bq = (const float*)d_in[4];
  const float* wk = (const float*)d_in[5];
  const float* bk = (const float*)d_in[6];
  const float* wv = (const float*)d_in[7];
  const float* bv = (const float*)d_in[8];
  const float* wp = (const float*)d_in[9];
  const float* bp = (const float*)d_in[10];
  float* out = (float*)d_out;
  float* ws  = (float*)d_ws;

  // units of CHW floats (4 MiB each):
  unsigned short* hT    = (unsigned short*)ws;                      // 0-1
  unsigned char*  qbp   = (unsigned char*)(ws + (size_t)2*CHW);     // 2 (fp8, 4 MB)
  unsigned char*  kbp   = (unsigned char*)(ws + (size_t)4*CHW);     // 4 (fp8, 4 MB)
  unsigned short* vbp   = (unsigned short*)(ws + (size_t)6*CHW);    // 6-7 (packed bf16)
  unsigned short* P1    = (unsigned short*)(ws + (size_t)8*CHW);    // 8-9
  unsigned short* P2    = (unsigned short*)(ws + (size_t)10*CHW);   // 10-11
  float*          l_arr = ws + (size_t)12*CHW;                      // 32768 floats
  unsigned short* wbuf  = (unsigned short*)(ws + (size_t)12*CHW + 65536); // 512 KB
  // Pm (merged P, bf16, 8 MB) reuses the q/k fp8 region [2CHW,4CHW) floats --
  // dead after att_kernel completes (stream-ordered before merge_kernel).
  unsigned short* Pm    = (unsigned short*)(ws + (size_t)2*CHW);

  unsigned short* wqb = wbuf;
  unsigned short* wkb = wbuf + 65536;
  unsigned short* wvb = wbuf + 2*65536;
  unsigned short* wpb = wbuf + 3*65536;

  gn_kernel<<<dim3(288), dim3(256), 0, stream>>>(x, gw, gb, hT, wq, wk, wv, wp, wbuf);
  qkv_kernel<<<dim3(64, 3, 4), dim3(256), 0, stream>>>(hT, wqb, bq, wkb, bk, wvb, bv, qbp, kbp, vbp);
  att_kernel<<<dim3(512), dim3(256), 0, stream>>>(qbp, kbp, vbp, P1, P2, l_arr);
  merge_kernel<<<dim3(2048), dim3(256), 0, stream>>>(P1, P2, l_arr, Pm);
  proj_kernel<<<dim3(512), dim3(256), 0, stream>>>(Pm, wpb, bp, x, out);
}

// Round 13
// 196.683 us; speedup vs baseline: 1.1101x; 1.0882x over previous
//
#include <hip/hip_runtime.h>

#define C 256
#define HW 4096
#define CHW (C*HW)            // 1048576 elements per batch per tensor (2^20)
#define CPG 8
#define GELEMS (CPG*HW)

typedef __attribute__((ext_vector_type(8))) short short8;     // 8 bf16 = 4 VGPRs
typedef __attribute__((ext_vector_type(4))) float floatx4;    // 16x16 C/D frag
typedef __attribute__((ext_vector_type(16))) float floatx16;  // 32x32 C/D frag

__device__ __forceinline__ unsigned short f2bf(float x) {
  union { float f; unsigned int u; } v; v.f = x;
  unsigned int r = v.u + 0x7FFF + ((v.u >> 16) & 1);   // RNE
  return (unsigned short)(r >> 16);
}
__device__ __forceinline__ float bf2f(unsigned short u) {
  union { float f; unsigned int v; } x; x.v = ((unsigned int)u) << 16; return x.f;
}
// exact e4m3fn (OCP) decode, branchless
__device__ __forceinline__ float fp8dec(unsigned int v) {
  unsigned int e = (v >> 3) & 15, m = v & 7;
  float mag = e ? ldexpf((float)(8 + m), (int)e - 10) : ldexpf((float)m, -9);
  return (v & 0x80) ? -mag : mag;
}

// ---------------- GroupNorm -> hT (b,s,c) bf16  +  weight cast ----------------
__global__ __launch_bounds__(256) void gn_kernel(const float* __restrict__ x,
    const float* __restrict__ gw, const float* __restrict__ gb,
    unsigned short* __restrict__ hT,
    const float* __restrict__ wq, const float* __restrict__ wk,
    const float* __restrict__ wv, const float* __restrict__ wp,
    unsigned short* __restrict__ wbuf) {
  int blk = blockIdx.x;
  int t = threadIdx.x;

  if (blk >= 256) {
    int r = blk - 256;
    int y = r >> 3, sub = r & 7;
    const float* src = (y == 0) ? wq : (y == 1) ? wk : (y == 2) ? wv : wp;
    int i = sub * 8192 + t * 4;
    float4 v = *(const float4*)(src + i);
    ushort4 u;
    u.x = f2bf(v.x); u.y = f2bf(v.y); u.z = f2bf(v.z); u.w = f2bf(v.w);
    *(ushort4*)(wbuf + y * 65536 + i) = u;
    return;
  }

  int gq = blk >> 1, halfg = blk & 1;   // group 0..127 (b*32+g), half 0/1
  int b = gq >> 5, g = gq & 31;
  const float* xg = x + (size_t)gq * GELEMS;
  const float4* x4 = (const float4*)xg;

  float s = 0.f, ss = 0.f;
  for (int i = t; i < GELEMS/4; i += 256) {
    float4 v = x4[i];
    s  += v.x + v.y + v.z + v.w;
    ss += v.x*v.x + v.y*v.y + v.z*v.z + v.w*v.w;
  }
  #pragma unroll
  for (int off = 32; off > 0; off >>= 1) {
    s  += __shfl_down(s,  off, 64);
    ss += __shfl_down(ss, off, 64);
  }
  __shared__ float rs[4], rss[4];
  __shared__ float smean, sinv;
  int wid = t >> 6;
  if ((t & 63) == 0) { rs[wid] = s; rss[wid] = ss; }
  __syncthreads();
  if (t == 0) {
    float S  = rs[0] + rs[1] + rs[2] + rs[3];
    float SS = rss[0] + rss[1] + rss[2] + rss[3];
    float mean = S / (float)GELEMS;
    float var  = SS / (float)GELEMS - mean * mean;
    smean = mean;
    sinv  = rsqrtf(var + 1e-5f);
  }
  __syncthreads();
  float mean = smean, inv = sinv;
  float sa[8], sb[8];
  #pragma unroll
  for (int cc = 0; cc < 8; ++cc) {
    sa[cc] = inv * gw[g*CPG + cc];
    sb[cc] = gb[g*CPG + cc] - mean * sa[cc];
  }
  int sbeg = halfg * 2048;
  #pragma unroll
  for (int p = 0; p < 8; ++p) {
    int sl = sbeg + p*256 + t;
    short8 pk;
    #pragma unroll
    for (int cc = 0; cc < 8; ++cc)
      pk[cc] = (short)f2bf(xg[cc*HW + sl] * sa[cc] + sb[cc]);
    *(short8*)&hT[((size_t)b*HW + sl) * 256 + g*CPG] = pk;
  }
}

// ---------------- fused QKV GEMM ----------
// q,k: fp8 e4m3 (s,c) layout, UNSCALED (C^-0.5 folded into att's exp).
// v: bf16 MFMA-B-fragment packed tiles (16s x 32c, 1 KB each).
__global__ __launch_bounds__(256) void qkv_kernel(const unsigned short* __restrict__ hT,
    const unsigned short* __restrict__ wqb, const float* __restrict__ bq,
    const unsigned short* __restrict__ wkb, const float* __restrict__ bk,
    const unsigned short* __restrict__ wvb, const float* __restrict__ bv,
    unsigned char* __restrict__ qo, unsigned char* __restrict__ ko,
    unsigned short* __restrict__ vo) {
  int stile = blockIdx.x, which = blockIdx.y, b = blockIdx.z;
  int t = threadIdx.x, w = t >> 6, lane = t & 63;
  int n16 = lane & 15, q8 = lane >> 4;
  int s0 = stile * 64;
  const unsigned short* hB = hT + (size_t)b * CHW;
  const unsigned short* W = (which == 0) ? wqb : (which == 1) ? wkb : wvb;
  const float* bias = (which == 0) ? bq : (which == 1) ? bk : bv;

  floatx4 acc[4][4];
  #pragma unroll
  for (int i = 0; i < 4; ++i)
    #pragma unroll
    for (int j = 0; j < 4; ++j) acc[i][j] = (floatx4){0.f,0.f,0.f,0.f};

  for (int kt = 0; kt < 8; ++kt) {
    short8 af[4], bf[4];
    #pragma unroll
    for (int mt = 0; mt < 4; ++mt)
      af[mt] = *(const short8*)&hB[(size_t)(s0 + mt*16 + n16) * 256 + kt*32 + q8*8];
    #pragma unroll
    for (int nt = 0; nt < 4; ++nt)
      bf[nt] = *(const short8*)&W[(size_t)(w*64 + nt*16 + n16) * 256 + kt*32 + q8*8];
    #pragma unroll
    for (int mt = 0; mt < 4; ++mt)
      #pragma unroll
      for (int nt = 0; nt < 4; ++nt)
        acc[mt][nt] = __builtin_amdgcn_mfma_f32_16x16x32_bf16(af[mt], bf[nt], acc[mt][nt], 0, 0, 0);
  }
  float bias_v[4];
  #pragma unroll
  for (int nt = 0; nt < 4; ++nt) bias_v[nt] = bias[w*64 + nt*16 + n16];

  if (which < 2) {
    // fp8 scatter stores (s,c); values unscaled
    unsigned char* oB = (which ? ko : qo) + (size_t)b * CHW;
    #pragma unroll
    for (int mt = 0; mt < 4; ++mt)
      #pragma unroll
      for (int nt = 0; nt < 4; ++nt) {
        float v0 = acc[mt][nt][0] + bias_v[nt];
        float v1 = acc[mt][nt][1] + bias_v[nt];
        float v2 = acc[mt][nt][2] + bias_v[nt];
        float v3 = acc[mt][nt][3] + bias_v[nt];
        unsigned int p01 = __builtin_amdgcn_cvt_pk_fp8_f32(v0, v1, 0, false);
        unsigned int p23 = __builtin_amdgcn_cvt_pk_fp8_f32(v2, v3, 0, false);
        int col = w*64 + nt*16 + n16;
        size_t r0 = (size_t)(s0 + mt*16 + q8*4) * 256 + col;
        oB[r0 +   0] = (unsigned char)(p01 & 0xFF);
        oB[r0 + 256] = (unsigned char)((p01 >> 8) & 0xFF);
        oB[r0 + 512] = (unsigned char)(p23 & 0xFF);
        oB[r0 + 768] = (unsigned char)((p23 >> 8) & 0xFF);
      }
  } else {
    // packed bf16 V store
    unsigned short* vB = vo + (size_t)b * CHW;
    #pragma unroll
    for (int mt = 0; mt < 4; ++mt) {
      int st = stile*4 + mt;
      #pragma unroll
      for (int nt = 0; nt < 4; ++nt) {
        int c = w*64 + nt*16 + n16;
        int ct8 = c >> 5, c5 = c & 31;
        #pragma unroll
        for (int r = 0; r < 4; ++r) {
          int sl = q8*4 + r;
          int hh = sl >> 3, e = sl & 7;
          vB[((size_t)st*8 + ct8)*512 + (hh*32 + c5)*8 + e] =
              f2bf(acc[mt][nt][r] + bias_v[nt]);
        }
      }
    }
  }
}

// ---------------- MFMA flash attention: fp8 QK, bf16 PV, split-K THIRDS ----
// r8 diagnosis: MfmaUtil pinned ~36% across all sync variants, occupancy 19%
// at 2 blocks/CU -> chain-latency-bound, TLP-starved. Fix: K split 2 -> 3
// (chunk ranges {0-11,11-22,22-32}); grid 768 = EXACTLY 3 blocks/CU
// (VGPR 104 + 64 AGPR = 168; 3x168 = 504 <= 512/SIMD). Wave structure and
// inner loop unchanged from the r3-measured-best form.
// Partials P1..P3 in fp8 e4m3 (Pi = Oi/li, O(1) range): 12 MB in the old
// 16 MB P slot, zero new workspace; att write traffic halves. Error adds
// ~1e-6 to out (convex merge + 1e-5 wp scale) vs 0.0156 baseline absmax.
// XCD decode: combos 0-7 pinned 1/XCD (bid<512); combos 8-11 split 2 XCDs.
#define KS8_PAD 264  // BYTES per Ks row (256 + 8); b64 reads 4 dwords/bank (min)
#define PS_PAD 72    // shorts per Ps row (64 + 8); b128 reads 8 dwords/bank (min)

__global__ __launch_bounds__(256, 2) void att_kernel(
    const unsigned char* __restrict__ qb,
    const unsigned char* __restrict__ kb,
    const unsigned short* __restrict__ vb,
    unsigned char* __restrict__ Pp,      // 3 partials, 4*CHW bytes apart
    float* __restrict__ l_arr) {
  __shared__ __align__(16) unsigned char Ks8[64 * KS8_PAD];   // 16.9 KB
  __shared__ __align__(16) unsigned short Ps[64 * PS_PAD];
  __shared__ float Ls[2][64];
  __shared__ float Lc[64];

  int t = threadIdx.x, w = t >> 6, lane = t & 63;
  int m32 = lane & 31;
  int h   = lane >> 5;
  int qblk = w & 1;
  int mblk = w >> 1;
  int bid = blockIdx.x;
  int combo, qt_idx;
  if (bid < 512) { combo = bid & 7; qt_idx = bid >> 3; }       // combos 0-7: 1 XCD each
  else { int r = bid - 512; combo = 8 + (r & 3); qt_idx = r >> 2; }
  int third = combo % 3, b = combo / 3;
  int n0 = qt_idx * 64;
  const int tb0[4] = {0, 11, 22, 32};
  int mc_beg = tb0[third], mc_end = tb0[third + 1];

  const unsigned char* qB = qb + (size_t)b * CHW;
  const unsigned char* kB = kb + (size_t)b * CHW;
  const unsigned short* vB = vb + (size_t)b * CHW;

  // Q fragments (fp8 A operand, 32x32x16): lane row n0+qblk*32+m32, k bytes h*8+e
  long qf8[16];
  {
    const unsigned char* qp = qB + (size_t)(n0 + qblk*32 + m32) * 256 + h*8;
    #pragma unroll
    for (int ks = 0; ks < 16; ++ks) qf8[ks] = *(const long*)(qp + ks*16);
  }

  float lsum[16];
  #pragma unroll
  for (int r = 0; r < 16; ++r) lsum[r] = 0.f;
  floatx16 oacc[2][2];   // [qt][ct]
  #pragma unroll
  for (int i = 0; i < 2; ++i)
    #pragma unroll
    for (int j = 0; j < 2; ++j)
      #pragma unroll
      for (int r = 0; r < 16; ++r) oacc[i][j][r] = 0.f;

  // staging: K chunk = 64 rows x 256 B; thread t covers row t>>2, 64 B at (t&3)*64
  int krow = t >> 2, kcb = (t & 3) * 64;
  uint4 kreg[4];
  #pragma unroll
  for (int i = 0; i < 4; ++i)
    kreg[i] = *(const uint4*)(kB + (size_t)(mc_beg*64 + krow) * 256 + kcb + i*16);

  for (int mc = mc_beg; mc < mc_end; ++mc) {
    int m0 = mc * 64;
    // stage current K chunk (b64 writes, pitch 264 B)
    #pragma unroll
    for (int i = 0; i < 4; ++i) {
      *(uint2*)&Ks8[krow * KS8_PAD + kcb + i*16]     = make_uint2(kreg[i].x, kreg[i].y);
      *(uint2*)&Ks8[krow * KS8_PAD + kcb + i*16 + 8] = make_uint2(kreg[i].z, kreg[i].w);
    }
    __syncthreads();
    // prefetch next K chunk
    if (mc + 1 < mc_end) {
      #pragma unroll
      for (int i = 0; i < 4; ++i)
        kreg[i] = *(const uint4*)(kB + (size_t)(m0 + 64 + krow) * 256 + kcb + i*16);
    }
    // V B-fragments: packed bf16 tiles, 1 coalesced b128 each
    short8 vreg[4][2];
    #pragma unroll
    for (int ks2 = 0; ks2 < 4; ++ks2)
      #pragma unroll
      for (int ct = 0; ct < 2; ++ct)
        vreg[ks2][ct] = *(const short8*)(vB +
            ((size_t)(mc*4 + ks2)*8 + (w*2 + ct))*512 + lane*8);

    // ---- S = Q·K^T (fp8): 2 independent 8-step chains ----
    floatx16 sa_, sb_;
    #pragma unroll
    for (int r = 0; r < 16; ++r) { sa_[r] = 0.f; sb_[r] = 0.f; }
    #pragma unroll
    for (int ks = 0; ks < 8; ++ks) {
      long bk0 = *(const long*)&Ks8[(mblk*32 + m32) * KS8_PAD + ks*16 + h*8];
      long bk1 = *(const long*)&Ks8[(mblk*32 + m32) * KS8_PAD + (ks+8)*16 + h*8];
      sa_ = __builtin_amdgcn_mfma_f32_32x32x16_fp8_fp8(qf8[ks],   bk0, sa_, 0, 0, 0);
      sb_ = __builtin_amdgcn_mfma_f32_32x32x16_fp8_fp8(qf8[ks+8], bk1, sb_, 0, 0, 0);
    }
    // ---- no-max softmax with C^-0.5 folded into exp; row reduction deferred ----
    #pragma unroll
    for (int reg = 0; reg < 16; ++reg) {
      float e = __expf((sa_[reg] + sb_[reg]) * 0.0625f);
      lsum[reg] += e;
      int qr = qblk*32 + (reg & 3) + 8*(reg >> 2) + 4*h;
      Ps[qr * PS_PAD + mblk*32 + m32] = f2bf(e);
    }
    __syncthreads();
    // ---- O += P·V (bf16) ----
    #pragma unroll
    for (int ks2 = 0; ks2 < 4; ++ks2) {
      short8 pf[2];
      #pragma unroll
      for (int qt = 0; qt < 2; ++qt)
        pf[qt] = *(const short8*)&Ps[(qt*32 + m32) * PS_PAD + ks2*16 + h*8];
      #pragma unroll
      for (int qt = 0; qt < 2; ++qt)
        #pragma unroll
        for (int ct = 0; ct < 2; ++ct)
          oacc[qt][ct] = __builtin_amdgcn_mfma_f32_32x32x16_bf16(pf[qt], vreg[ks2][ct], oacc[qt][ct], 0, 0, 0);
    }
  }

  // ---- epilogue: reduce l, normalize, write fp8 partial (s,c) + l ----
  #pragma unroll
  for (int reg = 0; reg < 16; ++reg) {
    float v = lsum[reg];
    v += __shfl_xor(v, 1);  v += __shfl_xor(v, 2);
    v += __shfl_xor(v, 4);  v += __shfl_xor(v, 8);
    v += __shfl_xor(v, 16);
    lsum[reg] = v;
  }
  if (m32 == 0) {
    #pragma unroll
    for (int reg = 0; reg < 16; ++reg) {
      int qr = qblk*32 + (reg & 3) + 8*(reg >> 2) + 4*h;
      Ls[mblk][qr] = lsum[reg];
    }
  }
  __syncthreads();
  if (t < 64) {
    float l = Ls[0][t] + Ls[1][t];
    l_arr[third * 16384 + b * 4096 + n0 + t] = l;
    Lc[t] = 1.f / l;
  }
  __syncthreads();
  unsigned char* pB = Pp + (size_t)third * 4 * CHW + (size_t)b * CHW;
  #pragma unroll
  for (int qt = 0; qt < 2; ++qt)
    #pragma unroll
    for (int rg = 0; rg < 16; rg += 2) {
      int q0 = qt*32 + (rg & 3) + 8*(rg >> 2) + 4*h;   // rows q0, q0+1
      float li0 = Lc[q0], li1 = Lc[q0 + 1];
      #pragma unroll
      for (int ct = 0; ct < 2; ++ct) {
        float a0 = oacc[qt][ct][rg]     * li0;
        float a1 = oacc[qt][ct][rg + 1] * li1;
        unsigned int pk = __builtin_amdgcn_cvt_pk_fp8_f32(a0, a1, 0, false);
        int col = w*64 + ct*32 + m32;
        size_t r0 = (size_t)(n0 + q0) * 256 + col;
        pB[r0]       = (unsigned char)(pk & 0xFF);
        pB[r0 + 256] = (unsigned char)((pk >> 8) & 0xFF);
      }
    }
}

// ---------------- merge kernel: Pm = (l1*P1+l2*P2+l3*P3)/(l1+l2+l3) --------
// fp8 partials in, bf16 out. Same HBM bytes as the r8 2-way bf16 merge.
__global__ __launch_bounds__(256) void merge_kernel(
    const unsigned char* __restrict__ Pp, const float* __restrict__ l_arr,
    unsigned short* __restrict__ Pm) {
  int row = blockIdx.x * 8 + (threadIdx.x >> 5);   // b*4096+s in [0,16384)
  int c0 = (threadIdx.x & 31) * 8;
  float l1 = l_arr[row], l2 = l_arr[16384 + row], l3 = l_arr[32768 + row];
  float inv = 1.f / (l1 + l2 + l3);
  float w1 = l1 * inv, w2 = l2 * inv, w3 = l3 * inv;
  size_t off = (size_t)row * 256 + c0;
  uint2 a = *(const uint2*)(Pp + off);
  uint2 b = *(const uint2*)(Pp + (size_t)4*CHW + off);
  uint2 c = *(const uint2*)(Pp + (size_t)8*CHW + off);
  short8 o;
  #pragma unroll
  for (int j = 0; j < 8; ++j) {
    unsigned int sh = (j & 3) * 8;
    unsigned int ba = ((j < 4 ? a.x : a.y) >> sh) & 0xFF;
    unsigned int bb = ((j < 4 ? b.x : b.y) >> sh) & 0xFF;
    unsigned int bc = ((j < 4 ? c.x : c.y) >> sh) & 0xFF;
    float val = w1 * fp8dec(ba) + w2 * fp8dec(bb) + w3 * fp8dec(bc);
    o[j] = (short)f2bf(val);
  }
  *(short8*)&Pm[off] = o;
}

// ---------------- proj GEMM + bias + residual, 512 blocks ----------------
// Clean GEMM on pre-merged Pm (b,s,c) bf16. XCD-aware decode as before.
__global__ __launch_bounds__(256) void proj_kernel(const unsigned short* __restrict__ Pm,
    const unsigned short* __restrict__ wpb, const float* __restrict__ bp,
    const float* __restrict__ x, float* __restrict__ out) {
  int bid = blockIdx.x;
  int combo = bid & 7, id = bid >> 3;
  int b = combo >> 1;
  int stile = (combo & 1) * 16 + (id & 15);
  int ox = id >> 4;
  int t = threadIdx.x, w = t >> 6, lane = t & 63;
  int n16 = lane & 15, q8 = lane >> 4;
  int o0 = ox * 64;
  int sBase = stile * 128 + w * 32;
  const unsigned short* pmB = Pm + (size_t)b * CHW;

  float4 bias4[4];
  #pragma unroll
  for (int mt = 0; mt < 4; ++mt)
    bias4[mt] = *(const float4*)&bp[o0 + mt*16 + q8*4];

  floatx4 acc[4][2];
  #pragma unroll
  for (int i = 0; i < 4; ++i)
    #pragma unroll
    for (int j = 0; j < 2; ++j) acc[i][j] = (floatx4){0.f,0.f,0.f,0.f};

  for (int kt = 0; kt < 8; ++kt) {
    short8 af[4], bf[2];
    #pragma unroll
    for (int mt = 0; mt < 4; ++mt)
      af[mt] = *(const short8*)&wpb[(size_t)(o0 + mt*16 + n16) * 256 + kt*32 + q8*8];
    #pragma unroll
    for (int nt = 0; nt < 2; ++nt)
      bf[nt] = *(const short8*)&pmB[(size_t)(sBase + nt*16 + n16) * 256 + kt*32 + q8*8];
    #pragma unroll
    for (int mt = 0; mt < 4; ++mt)
      #pragma unroll
      for (int nt = 0; nt < 2; ++nt)
        acc[mt][nt] = __builtin_amdgcn_mfma_f32_16x16x32_bf16(af[mt], bf[nt], acc[mt][nt], 0, 0, 0);
  }
  const float* xB = x + (size_t)b * CHW;
  float* oB = out + (size_t)b * CHW;
  #pragma unroll
  for (int mt = 0; mt < 4; ++mt)
    #pragma unroll
    for (int nt = 0; nt < 2; ++nt) {
      float bb[4] = {bias4[mt].x, bias4[mt].y, bias4[mt].z, bias4[mt].w};
      #pragma unroll
      for (int r = 0; r < 4; ++r) {
        size_t idx = (size_t)(o0 + mt*16 + q8*4 + r) * HW + sBase + nt*16 + n16;
        oB[idx] = xB[idx] + bb[r] + acc[mt][nt][r];
      }
    }
}

extern "C" void kernel_launch(void* const* d_in, const int* in_sizes, int n_in,
                              void* d_out, int out_size, void* d_ws, size_t ws_size,
                              hipStream_t stream) {
  const float* x  = (const float*)d_in[0];
  const float* gw = (const float*)d_in[1];
  const float* gb = (const float*)d_in[2];
  const float* wq = (const float*)d_in[3];
  const float* bq = (const float*)d_in[4];
  const float* wk = (const float*)d_in[5];
  const float* bk = (const float*)d_in[6];
  const float* wv = (const float*)d_in[7];
  const float* bv = (const float*)d_in[8];
  const float* wp = (const float*)d_in[9];
  const float* bp = (const float*)d_in[10];
  float* out = (float*)d_out;
  float* ws  = (float*)d_ws;

  // units of CHW floats (4 MiB each):
  unsigned short* hT    = (unsigned short*)ws;                      // 0-1
  unsigned char*  qbp   = (unsigned char*)(ws + (size_t)2*CHW);     // 2 (fp8, 1 MB)
  unsigned char*  kbp   = (unsigned char*)(ws + (size_t)4*CHW);     // 4 (fp8, 1 MB)
  unsigned short* vbp   = (unsigned short*)(ws + (size_t)6*CHW);    // 6-7 (packed bf16)
  unsigned char*  Pp    = (unsigned char*)(ws + (size_t)8*CHW);     // 8-10: 3 fp8 partials, 12 MB
  float*          l_arr = ws + (size_t)12*CHW;                      // 49152 floats (3 thirds)
  unsigned short* wbuf  = (unsigned short*)(ws + (size_t)12*CHW + 65536); // 512 KB
  // Pm (merged P, bf16, 8 MB) reuses the q/k fp8 region [2CHW,4CHW) floats --
  // dead after att_kernel completes (stream-ordered before merge_kernel).
  unsigned short* Pm    = (unsigned short*)(ws + (size_t)2*CHW);

  unsigned short* wqb = wbuf;
  unsigned short* wkb = wbuf + 65536;
  unsigned short* wvb = wbuf + 2*65536;
  unsigned short* wpb = wbuf + 3*65536;

  gn_kernel<<<dim3(288), dim3(256), 0, stream>>>(x, gw, gb, hT, wq, wk, wv, wp, wbuf);
  qkv_kernel<<<dim3(64, 3, 4), dim3(256), 0, stream>>>(hT, wqb, bq, wkb, bk, wvb, bv, qbp, kbp, vbp);
  att_kernel<<<dim3(768), dim3(256), 0, stream>>>(qbp, kbp, vbp, Pp, l_arr);
  merge_kernel<<<dim3(2048), dim3(256), 0, stream>>>(Pp, l_arr, Pm);
  proj_kernel<<<dim3(512), dim3(256), 0, stream>>>(Pm, wpb, bp, x, out);
}